// Round 6
// baseline (253.426 us; speedup 1.0000x reference)
//
#include <hip/hip_runtime.h>
#include <hip/hip_bf16.h>

// Problem constants
// B=64, N=256, IN=512, OUT=512, K_SLOTS=8, DK=64
// inputs: node_feats (64*256*512 f32), adj (64*8*256*256 f32), weight (512*512 f32), bias (512 f32)
// out: (64*256*512) f32

typedef __attribute__((ext_vector_type(8))) short short8;   // 8 bf16 (4 VGPRs) - MFMA A/B frag
typedef __attribute__((ext_vector_type(4))) float floatx4;  // MFMA C/D frag

__device__ __forceinline__ unsigned short f2bf(float f) {
    union { float f; unsigned u; } v; v.f = f;
    unsigned r = v.u + 0x7FFFu + ((v.u >> 16) & 1u);  // RNE
    return (unsigned short)(r >> 16);
}

// packed f32x2 -> bf16x2 (RNE); compiles to v_cvt_pk_bf16_f32 on gfx950
__device__ __forceinline__ unsigned pk2bf(float a, float b) {
    union { __hip_bfloat162 h; unsigned u; } cv;
    cv.h = __float22bfloat162_rn(make_float2(a, b));
    return cv.u;
}

// ---------------------------------------------------------------------------
// Pre-kernel: W (512x512, row-major [k][o]) -> Wt bf16 [o][k] (k contiguous)
// ---------------------------------------------------------------------------
__global__ __launch_bounds__(256) void wt_kernel(const float* __restrict__ W,
                                                 unsigned short* __restrict__ Wt) {
    __shared__ unsigned short t_lds[64 * 66];  // [o][k], pad 66 -> 2-way (free)
    const int tile = blockIdx.x;      // 0..63 (8x8 tiles)
    const int k0 = (tile >> 3) * 64;
    const int o0 = (tile & 7) * 64;
    const int t = threadIdx.x;
    const int c = t & 63;             // coalesced dim
    const int rb = t >> 6;            // 0..3
#pragma unroll
    for (int i = 0; i < 16; ++i) {
        int r = i * 4 + rb;           // k-row within tile
        t_lds[c * 66 + r] = f2bf(W[(size_t)(k0 + r) * 512 + o0 + c]);
    }
    __syncthreads();
#pragma unroll
    for (int i = 0; i < 16; ++i) {
        int o_r = i * 4 + rb;         // o-row within tile
        Wt[(size_t)(o0 + o_r) * 512 + k0 + c] = t_lds[o_r * 66 + c];
    }
}

// ---------------------------------------------------------------------------
// Fused kernel: one block per (b, ks). 1024 threads = 16 waves.
//   Stage 1: h_slice[256 m][64 d] = relu(X[b] @ Wt[ks*64.., :]^T + bias) -> LDS hT
//   Stage 2: out[b, n, ks*64+d] = sum_m adj[b,ks,n,m] * hT[d][m]
// Grid 512 (b = id&63 -> all 8 ks-blocks of a b on one XCD).
// 2 blocks/CU x 16 waves = 32 waves/CU = 100% occupancy ceiling (R5 was 50%):
// per-wave load windows unchanged, wave count x2 -> in-flight bytes x2.
// __launch_bounds__(1024, 8): force <=64 VGPR so 2 blocks/CU actually fit.
// ---------------------------------------------------------------------------
__global__ __launch_bounds__(1024, 8) void fused_kernel(
    const float* __restrict__ X, const unsigned short* __restrict__ Wt,
    const float* __restrict__ bias, const float* __restrict__ adj,
    float* __restrict__ out) {
    __shared__ union {
        struct {
            unsigned short a[256 * 40];  // X tile: 256 m x 32 k bf16, pad 40
            unsigned short w[64 * 40];   // W slice tile: 64 o x 32 k bf16
        } s1;
        unsigned short ht[64 * 264];     // hT: 64 d x 256 m bf16, pad 264 (16B-aligned rows)
    } lds;

    const int id = blockIdx.x;        // 0..511
    const int b = id & 63;            // same-b blocks == mod 8 -> same XCD
    const int ks = id >> 6;

    const int tid = threadIdx.x;
    const int lane = tid & 63, w = tid >> 6;   // wave 0..15
    const int lrow = lane & 15, quad = lane >> 4;

    const float* Xb = X + (size_t)b * 256 * 512;
    const unsigned short* Wslice = Wt + (size_t)ks * 64 * 512;  // [o_local][k]

    // ---------------- Stage 1: X[b] @ W-slice -> acc1 ----------------
    // wave tile: 16 m x 64 d
    floatx4 acc1[4];
    const floatx4 fzero = {0.f, 0.f, 0.f, 0.f};
#pragma unroll
    for (int j = 0; j < 4; ++j) acc1[j] = fzero;

    for (int kb = 0; kb < 16; ++kb) {
        const int k0 = kb * 32;
        // stage A: 256 m x 32 k = 2048 float4-chunks / 1024 threads
#pragma unroll
        for (int i = 0; i < 2; ++i) {
            int c4 = tid + i * 1024;         // 0..2047
            int rr = c4 >> 3;                // 0..255
            int cc = (c4 & 7) * 4;
            const float4 v = *(const float4*)(Xb + (size_t)rr * 512 + k0 + cc);
            unsigned p01 = pk2bf(v.x, v.y);
            unsigned p23 = pk2bf(v.z, v.w);
            unsigned* dst = (unsigned*)(lds.s1.a + rr * 40 + cc);
            dst[0] = p01; dst[1] = p23;
        }
        // stage W: 64 o x 32 k = 512 ushort4-chunks (half the threads)
        if (tid < 512) {
            int rr = tid >> 3;               // 0..63
            int cc = (tid & 7) * 4;
            *(ushort4*)(lds.s1.w + rr * 40 + cc) =
                *(const ushort4*)(Wslice + (size_t)rr * 512 + k0 + cc);
        }
        __syncthreads();

        short8 af, bfr[4];
        af = *(const short8*)(lds.s1.a + (w * 16 + lrow) * 40 + quad * 8);
#pragma unroll
        for (int j = 0; j < 4; ++j)
            bfr[j] = *(const short8*)(lds.s1.w + (16 * j + lrow) * 40 + quad * 8);
#pragma unroll
        for (int j = 0; j < 4; ++j)
            acc1[j] = __builtin_amdgcn_mfma_f32_16x16x32_bf16(af, bfr[j], acc1[j], 0, 0, 0);
        __syncthreads();
    }

    // ---------------- Stage 1 epilogue: bias+relu+bf16 -> lds.ht[d][m] ----------------
#pragma unroll
    for (int j = 0; j < 4; ++j) {
        int d = 16 * j + lrow;               // C/D col = lane&15
        float bv = bias[ks * 64 + d];
        int m = w * 16 + quad * 4;           // C/D row = quad*4+reg
        floatx4 c = acc1[j];
        unsigned p01 = pk2bf(fmaxf(c.x + bv, 0.f), fmaxf(c.y + bv, 0.f));
        unsigned p23 = pk2bf(fmaxf(c.z + bv, 0.f), fmaxf(c.w + bv, 0.f));
        unsigned* d32 = (unsigned*)(lds.ht + d * 264 + m);
        d32[0] = p01; d32[1] = p23;          // 8B store, 4 consecutive m
    }
    __syncthreads();

    // ---------------- Stage 2: adj[b,ks] @ hT -> out ----------------
    // wave tile: 16 n x 64 d
    const float* Abase = adj + ((size_t)(b * 8 + ks)) * 65536;  // [n][m] 256x256 f32
    const float* A0 = Abase + (size_t)(w * 16 + lrow) * 256;

    floatx4 acc2[4];
#pragma unroll
    for (int j = 0; j < 4; ++j) acc2[j] = fzero;

#pragma unroll
    for (int mt = 0; mt < 8; ++mt) {
        const int m0 = mt * 32 + quad * 8;
        const float* src = A0 + m0;
        float4 v0 = *(const float4*)src;
        float4 v1 = *(const float4*)(src + 4);
        union { short8 s; unsigned u[4]; } t;
        t.u[0] = pk2bf(v0.x, v0.y);
        t.u[1] = pk2bf(v0.z, v0.w);
        t.u[2] = pk2bf(v1.x, v1.y);
        t.u[3] = pk2bf(v1.z, v1.w);
        short8 af = t.s;
        short8 bfr[4];
#pragma unroll
        for (int j = 0; j < 4; ++j)
            bfr[j] = *(const short8*)(lds.ht + (16 * j + lrow) * 264 + m0);
#pragma unroll
        for (int j = 0; j < 4; ++j)
            acc2[j] = __builtin_amdgcn_mfma_f32_16x16x32_bf16(af, bfr[j], acc2[j], 0, 0, 0);
    }

    // epilogue: C/D layout col=lane&15 (d), row=quad*4+reg (n)
#pragma unroll
    for (int j = 0; j < 4; ++j) {
        int n = w * 16 + quad * 4;
        int d = 16 * j + lrow;
        float* dst = out + ((size_t)b * 256 + n) * 512 + ks * 64 + d;
        floatx4 c = acc2[j];
        dst[0 * 512] = c.x;
        dst[1 * 512] = c.y;
        dst[2 * 512] = c.z;
        dst[3 * 512] = c.w;
    }
}

// ---------------------------------------------------------------------------
extern "C" void kernel_launch(void* const* d_in, const int* in_sizes, int n_in,
                              void* d_out, int out_size, void* d_ws, size_t ws_size,
                              hipStream_t stream) {
    const float* X    = (const float*)d_in[0];  // node_feats
    const float* adj  = (const float*)d_in[1];  // adj
    const float* W    = (const float*)d_in[2];  // weight
    const float* bias = (const float*)d_in[3];  // bias
    float* out = (float*)d_out;

    // workspace: Wt bf16 [512*512] only
    unsigned short* Wt = (unsigned short*)d_ws;

    wt_kernel<<<64, 256, 0, stream>>>(W, Wt);
    fused_kernel<<<512, 1024, 0, stream>>>(X, Wt, bias, adj, out);
}

// Round 7
// 249.418 us; speedup vs baseline: 1.0161x; 1.0161x over previous
//
#include <hip/hip_runtime.h>
#include <hip/hip_bf16.h>

// Problem constants
// B=64, N=256, IN=512, OUT=512, K_SLOTS=8, DK=64
// inputs: node_feats (64*256*512 f32), adj (64*8*256*256 f32), weight (512*512 f32), bias (512 f32)
// out: (64*256*512) f32

typedef __attribute__((ext_vector_type(8))) short short8;   // 8 bf16 (4 VGPRs) - MFMA A/B frag
typedef __attribute__((ext_vector_type(4))) float floatx4;  // MFMA C/D frag

__device__ __forceinline__ unsigned short f2bf(float f) {
    union { float f; unsigned u; } v; v.f = f;
    unsigned r = v.u + 0x7FFFu + ((v.u >> 16) & 1u);  // RNE
    return (unsigned short)(r >> 16);
}

// packed f32x2 -> bf16x2 (RNE); compiles to v_cvt_pk_bf16_f32 on gfx950
__device__ __forceinline__ unsigned pk2bf(float a, float b) {
    union { __hip_bfloat162 h; unsigned u; } cv;
    cv.h = __float22bfloat162_rn(make_float2(a, b));
    return cv.u;
}

// ---------------------------------------------------------------------------
// Pre-kernel: W (512x512, row-major [k][o]) -> Wt bf16 [o][k] (k contiguous)
// ---------------------------------------------------------------------------
__global__ __launch_bounds__(256) void wt_kernel(const float* __restrict__ W,
                                                 unsigned short* __restrict__ Wt) {
    __shared__ unsigned short t_lds[64 * 66];  // [o][k], pad 66 -> 2-way (free)
    const int tile = blockIdx.x;      // 0..63 (8x8 tiles)
    const int k0 = (tile >> 3) * 64;
    const int o0 = (tile & 7) * 64;
    const int t = threadIdx.x;
    const int c = t & 63;             // coalesced dim
    const int rb = t >> 6;            // 0..3
#pragma unroll
    for (int i = 0; i < 16; ++i) {
        int r = i * 4 + rb;           // k-row within tile
        t_lds[c * 66 + r] = f2bf(W[(size_t)(k0 + r) * 512 + o0 + c]);
    }
    __syncthreads();
#pragma unroll
    for (int i = 0; i < 16; ++i) {
        int o_r = i * 4 + rb;         // o-row within tile
        Wt[(size_t)(o0 + o_r) * 512 + k0 + c] = t_lds[o_r * 66 + c];
    }
}

// ---------------------------------------------------------------------------
// Fused kernel: one block per (b, ks). 1024 threads = 16 waves, 2 blocks/CU.
//   Stage 1: h_slice = relu(X[b] @ Wslice^T + bias) -> LDS ht (bf16, swizzled)
//   Stage 2: adj[b,ks] streamed LINEARLY through LDS tiles (64 n-rows = 64 KB
//            contiguous per tile), bf16-convert in flight, MFMA from LDS.
// LDS layouts (stage 2) use 16-B block XOR swizzle: row stride 512 B (no pad),
// block jm at physical slot jm ^ (row & 7) -> uniform banks for b128 ops.
// ht(32 KB) + adj tile(32 KB) = 64 KB exactly; stage-1 tiles live in a union.
// ---------------------------------------------------------------------------
__global__ __launch_bounds__(1024, 8) void fused_kernel(
    const float* __restrict__ X, const unsigned short* __restrict__ Wt,
    const float* __restrict__ bias, const float* __restrict__ adj,
    float* __restrict__ out) {
    __shared__ union {
        struct {
            unsigned short a[256 * 40];  // X tile: 256 m x 32 k bf16, pad 40
            unsigned short w[64 * 40];   // W slice tile: 64 o x 32 k bf16
        } s1;
        struct {
            unsigned short ht[64 * 256]; // hT [d][m] bf16, swizzled blocks
            unsigned short at[64 * 256]; // adj tile [n_loc][m] bf16, swizzled
        } s2;
    } lds;

    const int id = blockIdx.x;        // 0..511
    const int b = id & 63;            // same-b blocks == mod 8 -> same XCD
    const int ks = id >> 6;

    const int tid = threadIdx.x;
    const int lane = tid & 63, w = tid >> 6;   // wave 0..15
    const int lrow = lane & 15, quad = lane >> 4;

    const float* Xb = X + (size_t)b * 256 * 512;
    const unsigned short* Wslice = Wt + (size_t)ks * 64 * 512;  // [o_local][k]

    // ---------------- Stage 1: X[b] @ W-slice -> acc1 (wave tile 16m x 64d) --
    floatx4 acc1[4];
    const floatx4 fzero = {0.f, 0.f, 0.f, 0.f};
#pragma unroll
    for (int j = 0; j < 4; ++j) acc1[j] = fzero;

    for (int kb = 0; kb < 16; ++kb) {
        const int k0 = kb * 32;
        // stage A: 256 m x 32 k = 2048 float4-chunks / 1024 threads
#pragma unroll
        for (int i = 0; i < 2; ++i) {
            int c4 = tid + i * 1024;         // 0..2047
            int rr = c4 >> 3;                // 0..255
            int cc = (c4 & 7) * 4;
            const float4 v = *(const float4*)(Xb + (size_t)rr * 512 + k0 + cc);
            unsigned p01 = pk2bf(v.x, v.y);
            unsigned p23 = pk2bf(v.z, v.w);
            unsigned* dst = (unsigned*)(lds.s1.a + rr * 40 + cc);
            dst[0] = p01; dst[1] = p23;
        }
        // stage W: 64 o x 32 k = 512 ushort4-chunks (waves 0-7 only)
        if (tid < 512) {
            int rr = tid >> 3;               // 0..63
            int cc = (tid & 7) * 4;
            *(ushort4*)(lds.s1.w + rr * 40 + cc) =
                *(const ushort4*)(Wslice + (size_t)rr * 512 + k0 + cc);
        }
        __syncthreads();

        short8 af, bfr[4];
        af = *(const short8*)(lds.s1.a + (w * 16 + lrow) * 40 + quad * 8);
#pragma unroll
        for (int j = 0; j < 4; ++j)
            bfr[j] = *(const short8*)(lds.s1.w + (16 * j + lrow) * 40 + quad * 8);
#pragma unroll
        for (int j = 0; j < 4; ++j)
            acc1[j] = __builtin_amdgcn_mfma_f32_16x16x32_bf16(af, bfr[j], acc1[j], 0, 0, 0);
        __syncthreads();
    }

    // ------------- Stage 1 epilogue: bias+relu+bf16 -> swizzled ht[d][m] -----
#pragma unroll
    for (int j = 0; j < 4; ++j) {
        int d = 16 * j + lrow;               // C/D col = lane&15
        float bv = bias[ks * 64 + d];
        int m = w * 16 + quad * 4;           // C/D row = quad*4+reg
        floatx4 c = acc1[j];
        unsigned p01 = pk2bf(fmaxf(c.x + bv, 0.f), fmaxf(c.y + bv, 0.f));
        unsigned p23 = pk2bf(fmaxf(c.z + bv, 0.f), fmaxf(c.w + bv, 0.f));
        int jm = 2 * w + (quad >> 1);        // 16-B block index = m>>3
        int phys = jm ^ (d & 7);             // XOR swizzle
        unsigned* d32 = (unsigned*)(lds.s2.ht + d * 256 + phys * 8 + (quad & 1) * 4);
        d32[0] = p01; d32[1] = p23;          // 8B store
    }
    __syncthreads();

    // ------------- Stage 2: adj[b,ks] @ ht -> out, 4 n-tiles of 64 rows ------
    const float* Abase = adj + ((size_t)(b * 8 + ks)) * 65536;  // [n][m] 256x256 f32
    const int wn = w & 3, wd = w >> 2;       // wave tile: 16n x 16d

    for (int nt = 0; nt < 4; ++nt) {
        // staging: 64 rows x 256 m = 64 KB fp32, PURE LINEAR stream.
        // thread chunk c = 8 floats (32 B); consecutive threads consecutive addrs.
#pragma unroll
        for (int s = 0; s < 2; ++s) {
            int c = s * 1024 + tid;          // 0..2047
            int nl = c >> 5;                 // 0..63
            int jm = c & 31;                 // 16-B bf16 block within row
            const float* src = Abase + ((size_t)(nt * 64 + nl)) * 256 + jm * 8;
            float4 v0 = *(const float4*)src;
            float4 v1 = *(const float4*)(src + 4);
            union { short8 sh; unsigned u[4]; } t;
            t.u[0] = pk2bf(v0.x, v0.y);
            t.u[1] = pk2bf(v0.z, v0.w);
            t.u[2] = pk2bf(v1.x, v1.y);
            t.u[3] = pk2bf(v1.z, v1.w);
            *(short8*)(lds.s2.at + nl * 256 + ((jm ^ (nl & 7)) * 8)) = t.sh;
        }
        __syncthreads();

        floatx4 acc = fzero;
        const int nl = wn * 16 + lrow;       // A-row (n within tile)
        const int d  = wd * 16 + lrow;       // B-row (d)
#pragma unroll
        for (int mt = 0; mt < 8; ++mt) {
            int jm = 4 * mt + quad;          // k-block = (mt*32 + quad*8)/8
            short8 afr = *(const short8*)(lds.s2.at + nl * 256 + ((jm ^ (lrow & 7)) * 8));
            short8 bfr = *(const short8*)(lds.s2.ht + d  * 256 + ((jm ^ (lrow & 7)) * 8));
            acc = __builtin_amdgcn_mfma_f32_16x16x32_bf16(afr, bfr, acc, 0, 0, 0);
        }
        __syncthreads();   // at consumed; next tile may restage

        // epilogue: C/D col = lane&15 (d), row = quad*4+reg (n)
        int n_g = nt * 64 + wn * 16 + quad * 4;
        float* dst = out + ((size_t)b * 256 + n_g) * 512 + ks * 64 + wd * 16 + lrow;
        dst[0 * 512] = acc.x;
        dst[1 * 512] = acc.y;
        dst[2 * 512] = acc.z;
        dst[3 * 512] = acc.w;
    }
}

// ---------------------------------------------------------------------------
extern "C" void kernel_launch(void* const* d_in, const int* in_sizes, int n_in,
                              void* d_out, int out_size, void* d_ws, size_t ws_size,
                              hipStream_t stream) {
    const float* X    = (const float*)d_in[0];  // node_feats
    const float* adj  = (const float*)d_in[1];  // adj
    const float* W    = (const float*)d_in[2];  // weight
    const float* bias = (const float*)d_in[3];  // bias
    float* out = (float*)d_out;

    // workspace: Wt bf16 [512*512] only
    unsigned short* Wt = (unsigned short*)d_ws;

    wt_kernel<<<64, 256, 0, stream>>>(W, Wt);
    fused_kernel<<<512, 1024, 0, stream>>>(X, Wt, bias, adj, out);
}